// Round 13
// baseline (153.828 us; speedup 1.0000x reference)
//
#include <hip/hip_runtime.h>

#define DEV __device__ __forceinline__

typedef __attribute__((ext_vector_type(8))) short short8v;
typedef __attribute__((ext_vector_type(4))) float f32x4;

DEV unsigned short bfr(float f) {                 // fp32 -> bf16 RNE (weights)
    unsigned u = __float_as_uint(f);
    return (unsigned short)((u + 0x7fffu + ((u >> 16) & 1u)) >> 16);
}
DEV short bft(float f) { return (short)(__float_as_uint(f) >> 16); } // truncate (activations)
DEV float bf2f(unsigned short h) { return __uint_as_float(((unsigned)h) << 16); }
DEV float frcp(float x) { return __builtin_amdgcn_rcpf(x); }
DEV float ftanh(float x) { float e = __expf(2.0f * x); return 1.0f - 2.0f * frcp(e + 1.0f); }

constexpr int NN = 4096, TT = 128;
constexpr int BATCH = 8, NB = TT / BATCH;   // 16 batches

#define MFMA32(a, b, c) __builtin_amdgcn_mfma_f32_16x16x32_bf16(a, b, c, 0, 0, 0)

// R13: 9 waves. Wave 0 = scanner (serial recurrence only; enc prefetched,
// 16 back-to-back MFMAs = ONE wait boundary, tree combine). Waves 1-8 =
// consumers, EXACTLY ONE phi step per batch each (R9-R12 fit: consumer
// serial-chain count per interval is on the critical path; R9's k=2 beat
// R10/R11's k=3; this is k=1). Barriers, not LDS flag polling (R12: polling
// DS contention). MFMA-based epilogue reduction (R10). Permuted-feature
// in-lane chaining as R6-R12. No lambdas / no asm memory clobbers (R8).

__global__ __launch_bounds__(576) __attribute__((amdgpu_waves_per_eu(2)))
void wfa_kernel(
    const float* __restrict__ x,
    const float* __restrict__ e1w, const float* __restrict__ e1b,
    const float* __restrict__ e2w, const float* __restrict__ e2b,
    const float* __restrict__ A,
    const float* __restrict__ initw,
    const float* __restrict__ n1w, const float* __restrict__ n1b,
    const float* __restrict__ n2w, const float* __restrict__ n2b,
    const float* __restrict__ muw, const float* __restrict__ mub,
    const float* __restrict__ sgw, const float* __restrict__ sgb,
    const float* __restrict__ alw, const float* __restrict__ alb,
    float* __restrict__ out)
{
    __shared__ __align__(16) unsigned short enc_l[TT * 128];   // [t][n*8+d] bf16, 32KB
    __shared__ __align__(16) float x_l[16 * 130];              // [n][t]
    __shared__ __align__(16) short8v ring_l[2][BATCH][64];     // tmp frags, 16KB
    __shared__ __align__(16) float n1b_l[64], n2b_l[64], hb_l[48];
    __shared__ float part_l[9][16];

    const int tid = threadIdx.x;
    const int wv = tid >> 6, lane = tid & 63;
    const int quad = lane >> 4, col = lane & 15;
    const int n0 = blockIdx.x * 16;
    const f32x4 z4 = {0.f, 0.f, 0.f, 0.f};

    // ---- stage x + biases ----
    for (int i = tid; i < 16 * TT; i += 576)
        x_l[(i >> 7) * 130 + (i & 127)] = x[(n0 + (i >> 7)) * TT + (i & 127)];
    if (tid < 64) { n1b_l[tid] = n1b[tid]; n2b_l[tid] = n2b[tid]; }
    if (tid >= 64 && tid < 112) {
        const int i = tid - 64, mt = i >> 4, k = i & 15;
        hb_l[i] = (k < 10) ? ((mt == 0) ? mub[k] : (mt == 1) ? sgb[k] : alb[k]) : 0.f;
    }
    __syncthreads();   // x_l ready

    // ---- encoder: waves 0-7 own tile wv; wave 8 skips ----
    if (wv < 8) {
        float e1c[16], e1bc[16];
        #pragma unroll
        for (int kc = 0; kc < 2; ++kc)
            #pragma unroll
            for (int jj = 0; jj < 8; ++jj) {
                const int f = kc * 32 + (jj >> 2) * 16 + quad * 4 + (jj & 3);
                e1c[kc * 8 + jj] = e1w[f];
                e1bc[kc * 8 + jj] = e1b[f];
            }
        short8v E2A[2];   // A[m=d(col<8)][k=h feature, permuted]
        #pragma unroll
        for (int kc = 0; kc < 2; ++kc)
            #pragma unroll
            for (int jj = 0; jj < 8; ++jj)
                E2A[kc][jj] = (short)(col < 8
                    ? bfr(e2w[(kc * 32 + (jj >> 2) * 16 + quad * 4 + (jj & 3)) * 8 + col]) : 0);
        float e2bc[4];
        #pragma unroll
        for (int r = 0; r < 4; ++r) e2bc[r] = (quad < 2) ? e2b[quad * 4 + r] : 0.f;

        const int tbase = wv * 16;
        #pragma unroll 1
        for (int nn = 0; nn < 16; ++nn) {
            const float xs = x_l[nn * 130 + tbase + col];
            short8v eB[2];
            #pragma unroll
            for (int kc = 0; kc < 2; ++kc)
                #pragma unroll
                for (int jj = 0; jj < 8; ++jj)
                    eB[kc][jj] = bft(fmaxf(fmaf(xs, e1c[kc * 8 + jj], e1bc[kc * 8 + jj]), 0.f));
            f32x4 d = MFMA32(E2A[0], eB[0], z4);
            d = MFMA32(E2A[1], eB[1], d);
            if (quad < 2) {
                #pragma unroll
                for (int r = 0; r < 4; ++r)
                    enc_l[(tbase + col) * 128 + nn * 8 + quad * 4 + r] = bfr(ftanh(d[r] + e2bc[r]));
            }
        }
    }
    __syncthreads();   // enc_l ready

    if (wv == 0) {
        // =========================== SCANNER ===========================
        short8v A2f[16];   // out m=mt*16+col -> d=mt>>1, j-half=mt&1; k=i (permuted)
        #pragma unroll
        for (int mt = 0; mt < 16; ++mt)
            #pragma unroll
            for (int jj = 0; jj < 8; ++jj)
                A2f[mt][jj] = (short)bfr(
                    A[((jj >> 2) * 16 + quad * 4 + (jj & 3)) * 256 + (mt >> 1) * 32 + (mt & 1) * 16 + col]);

        short8v tmpB;
        #pragma unroll
        for (int jj = 0; jj < 8; ++jj)
            tmpB[jj] = (short)bfr(initw[(jj >> 2) * 16 + quad * 4 + (jj & 3)]);

        asm volatile("s_setprio 2");

        float evc[8];   // ev(enc[0]) for advance t=1, converted off-chain
        {
            const short8v e80 = *(const short8v*)&enc_l[0 * 128 + col * 8];
            #pragma unroll
            for (int d = 0; d < 8; ++d) evc[d] = bf2f((unsigned short)e80[d]);
        }

        #pragma unroll 1
        for (int b = 0; b <= NB; ++b) {
            if (b < NB) {
                #pragma unroll 1
                for (int i = 0; i < BATCH; ++i) {
                    const int t = b * BATCH + i;
                    if (t > 0) {
                        const short8v e8n = *(const short8v*)&enc_l[t * 128 + col * 8]; // for t+1
                        f32x4 D[16];
                        #pragma unroll
                        for (int mt = 0; mt < 16; ++mt) D[mt] = MFMA32(A2f[mt], tmpB, z4);
                        short8v nt;
                        #pragma unroll
                        for (int h = 0; h < 2; ++h)
                            #pragma unroll
                            for (int r = 0; r < 4; ++r) {   // tree combine, D tile mt=2d+h
                                const float p0 = fmaf(evc[1], D[2 + h][r], evc[0] * D[h][r]);
                                const float p1 = fmaf(evc[3], D[6 + h][r], evc[2] * D[4 + h][r]);
                                const float p2 = fmaf(evc[5], D[10 + h][r], evc[4] * D[8 + h][r]);
                                const float p3 = fmaf(evc[7], D[14 + h][r], evc[6] * D[12 + h][r]);
                                nt[h * 4 + r] = bft((p0 + p1) + (p2 + p3));
                            }
                        tmpB = nt;
                        #pragma unroll
                        for (int d = 0; d < 8; ++d) evc[d] = bf2f((unsigned short)e8n[d]);
                    }
                    ring_l[b & 1][i][lane] = tmpB;
                }
            }
            __syncthreads();
        }
        if (lane < 16) part_l[0][lane] = 0.f;
    } else {
        // ============== CONSUMERS: wave wv handles step i = wv-1 ==============
        short8v W1f[4];    // h1 out = mt*16+col, k = th feature (permuted)
        #pragma unroll
        for (int mt = 0; mt < 4; ++mt)
            #pragma unroll
            for (int jj = 0; jj < 8; ++jj)
                W1f[mt][jj] = (short)bfr(n1w[((jj >> 2) * 16 + quad * 4 + (jj & 3)) * 64 + mt * 16 + col]);
        short8v W2f[4][2];
        #pragma unroll
        for (int mt = 0; mt < 4; ++mt)
            #pragma unroll
            for (int kb = 0; kb < 2; ++kb)
                #pragma unroll
                for (int jj = 0; jj < 8; ++jj)
                    W2f[mt][kb][jj] = (short)bfr(
                        n2w[(kb * 32 + (jj >> 2) * 16 + quad * 4 + (jj & 3)) * 64 + mt * 16 + col]);
        short8v Whf[3][2]; // 0=mu,1=sig,2=alpha; out m = head idx (col<10)
        #pragma unroll
        for (int mt = 0; mt < 3; ++mt) {
            const float* Wh = (mt == 0) ? muw : (mt == 1) ? sgw : alw;
            #pragma unroll
            for (int kb = 0; kb < 2; ++kb)
                #pragma unroll
                for (int jj = 0; jj < 8; ++jj)
                    Whf[mt][kb][jj] = (short)(col < 10
                        ? bfr(Wh[(kb * 32 + (jj >> 2) * 16 + quad * 4 + (jj & 3)) * 10 + col]) : 0);
        }
        // epilogue selection matrix: D row m%4==0 sums e1 slots (jj<4) of valid
        // heads -> s1; m%4==1 sums e2 slots (jj>=4) -> s2 (verified R10).
        short8v AselF;
        #pragma unroll
        for (int jj = 0; jj < 8; ++jj) {
            const int h = quad * 4 + (jj & 3), half = jj >> 2;
            const int want = (col & 3);
            AselF[jj] = (short)((h < 10 && ((want == 0 && half == 0) || (want == 1 && half == 1)))
                                ? 0x3F80 : 0);
        }

        float res2 = 0.f;
        const float CST = 0.91893853320467274f;
        const int i = wv - 1;   // this wave's step within every batch

        #pragma unroll 1
        for (int b = 0; b <= NB; ++b) {
            if (b >= 1) {
                const int t = (b - 1) * BATCH + i;
                const short8v tf = ring_l[(b - 1) & 1][i][lane];
                short8v thB;
                #pragma unroll
                for (int jj = 0; jj < 8; ++jj)
                    thB[jj] = bft(ftanh(bf2f((unsigned short)tf[jj])));

                // h1 = relu(W1^T @ th + b1)   (bias as C operand)
                short8v h1B[2];
                #pragma unroll
                for (int mt = 0; mt < 4; ++mt) {
                    const f32x4 c = *(const f32x4*)&n1b_l[mt * 16 + quad * 4];
                    const f32x4 d = MFMA32(W1f[mt], thB, c);
                    #pragma unroll
                    for (int r = 0; r < 4; ++r)
                        h1B[mt >> 1][(mt & 1) * 4 + r] = bft(fmaxf(d[r], 0.f));
                }
                // h2 = relu(W2^T @ h1 + b2)
                short8v h2B[2];
                #pragma unroll
                for (int mt = 0; mt < 4; ++mt) {
                    const f32x4 c = *(const f32x4*)&n2b_l[mt * 16 + quad * 4];
                    f32x4 d = MFMA32(W2f[mt][0], h1B[0], c);
                    d = MFMA32(W2f[mt][1], h1B[1], d);
                    #pragma unroll
                    for (int r = 0; r < 4; ++r)
                        h2B[mt >> 1][(mt & 1) * 4 + r] = bft(fmaxf(d[r], 0.f));
                }
                // heads; lane holds heads quad*4+r for sample col
                f32x4 hd[3];
                #pragma unroll
                for (int mt = 0; mt < 3; ++mt) {
                    const f32x4 c = *(const f32x4*)&hb_l[mt * 16 + quad * 4];
                    f32x4 d = MFMA32(Whf[mt][0], h2B[0], c);
                    hd[mt] = MFMA32(Whf[mt][1], h2B[1], d);
                }
                // epilogue: exp terms packed bf16; ONE MFMA does both sums.
                // (no-max logsumexp: terms O(1); underflow->0 == reference's 0)
                const float xt = x_l[col * 130 + t];
                short8v eBv;
                #pragma unroll
                for (int r = 0; r < 4; ++r) {
                    const float mu = hd[0][r], sg = hd[1][r], la = hd[2][r];
                    const float z = (xt - mu) * __expf(-sg);
                    eBv[r]     = bft(__expf(la));
                    eBv[4 + r] = bft(__expf(la - sg - fmaf(0.5f * z, z, CST)));
                }
                const f32x4 dsum = MFMA32(AselF, eBv, z4);   // [0]=s1, [1]=s2
                res2 += __log2f(dsum[1]) - __log2f(dsum[0]);
            }
            __syncthreads();
        }
        if (lane < 16) part_l[wv][lane] = res2;   // identical across quads
    }

    __syncthreads();
    if (tid < 16) {
        float s = 0.f;
        #pragma unroll
        for (int w = 0; w < 9; ++w) s += part_l[w][tid];
        out[n0 + tid] = exp2f(s);
    }
}

extern "C" void kernel_launch(void* const* d_in, const int* in_sizes, int n_in,
                              void* d_out, int out_size, void* d_ws, size_t ws_size,
                              hipStream_t stream) {
    wfa_kernel<<<dim3(NN / 16), dim3(576), 0, stream>>>(
        (const float*)d_in[0],  (const float*)d_in[1],  (const float*)d_in[2],
        (const float*)d_in[3],  (const float*)d_in[4],  (const float*)d_in[5],
        (const float*)d_in[6],  (const float*)d_in[7],  (const float*)d_in[8],
        (const float*)d_in[9],  (const float*)d_in[10], (const float*)d_in[11],
        (const float*)d_in[12], (const float*)d_in[13], (const float*)d_in[14],
        (const float*)d_in[15], (const float*)d_in[16], (float*)d_out);
}

// Round 14
// 146.525 us; speedup vs baseline: 1.0498x; 1.0498x over previous
//
#include <hip/hip_runtime.h>

#define DEV __device__ __forceinline__

typedef __attribute__((ext_vector_type(8))) short short8v;
typedef __attribute__((ext_vector_type(4))) float f32x4;

DEV unsigned short bfr(float f) {                 // fp32 -> bf16 RNE (weights)
    unsigned u = __float_as_uint(f);
    return (unsigned short)((u + 0x7fffu + ((u >> 16) & 1u)) >> 16);
}
DEV short bft(float f) { return (short)(__float_as_uint(f) >> 16); } // truncate (activations)
DEV float bf2f(unsigned short h) { return __uint_as_float(((unsigned)h) << 16); }
DEV float frcp(float x) { return __builtin_amdgcn_rcpf(x); }
DEV float ftanh(float x) { float e = __expf(2.0f * x); return 1.0f - 2.0f * frcp(e + 1.0f); }

constexpr int NN = 4096, TT = 128;
constexpr int BATCH = 16, NB = TT / BATCH;   // 8 batches, 9 intervals

#define MFMA32(a, b, c) __builtin_amdgcn_mfma_f32_16x16x32_bf16(a, b, c, 0, 0, 0)

// R14: 8 waves (512 thr, R9's best geometry). Wave 0 = scanner; wave 4 (the
// scanner's SIMD0-mate under round-robin wave placement) IDLES in steady state
// so the scanner gets ~exclusive issue bandwidth on SIMD0 (R13 fit: per-advance
// cost scales with waves sharing the SIMD: 1060 @2 waves, 1360 @3). Waves
// {1,2,3,5,6,7} = consumers on SIMDs 1-3, <=3 chains per interval. BATCH=16
// -> 9 barrier intervals (R10's BATCH=16 loss was its k=3, not batch size).
// MFMA epilogue reduction (R10), single-wait advance + tree combine (R13).
// No lambdas / no asm memory clobbers (R8: scratch blowup).

__global__ __launch_bounds__(512) __attribute__((amdgpu_waves_per_eu(2)))
void wfa_kernel(
    const float* __restrict__ x,
    const float* __restrict__ e1w, const float* __restrict__ e1b,
    const float* __restrict__ e2w, const float* __restrict__ e2b,
    const float* __restrict__ A,
    const float* __restrict__ initw,
    const float* __restrict__ n1w, const float* __restrict__ n1b,
    const float* __restrict__ n2w, const float* __restrict__ n2b,
    const float* __restrict__ muw, const float* __restrict__ mub,
    const float* __restrict__ sgw, const float* __restrict__ sgb,
    const float* __restrict__ alw, const float* __restrict__ alb,
    float* __restrict__ out)
{
    __shared__ __align__(16) unsigned short enc_l[TT * 128];   // [t][n*8+d] bf16, 32KB
    __shared__ __align__(16) float x_l[16 * 130];              // [n][t]
    __shared__ __align__(16) short8v ring_l[2][BATCH][64];     // tmp frags, 32KB
    __shared__ __align__(16) float n1b_l[64], n2b_l[64], hb_l[48];
    __shared__ float part_l[8][16];

    const int tid = threadIdx.x;
    const int wv = tid >> 6, lane = tid & 63;
    const int quad = lane >> 4, col = lane & 15;
    const int n0 = blockIdx.x * 16;
    const f32x4 z4 = {0.f, 0.f, 0.f, 0.f};

    // ---- stage x + biases ----
    for (int i = tid; i < 16 * TT; i += 512)
        x_l[(i >> 7) * 130 + (i & 127)] = x[(n0 + (i >> 7)) * TT + (i & 127)];
    if (tid < 64) { n1b_l[tid] = n1b[tid]; n2b_l[tid] = n2b[tid]; }
    if (tid >= 64 && tid < 112) {
        const int i = tid - 64, mt = i >> 4, k = i & 15;
        hb_l[i] = (k < 10) ? ((mt == 0) ? mub[k] : (mt == 1) ? sgb[k] : alb[k]) : 0.f;
    }
    __syncthreads();   // x_l ready

    // ---- encoder: wave wv owns t-tile wv (all 8 waves) ----
    {
        float e1c[16], e1bc[16];
        #pragma unroll
        for (int kc = 0; kc < 2; ++kc)
            #pragma unroll
            for (int jj = 0; jj < 8; ++jj) {
                const int f = kc * 32 + (jj >> 2) * 16 + quad * 4 + (jj & 3);
                e1c[kc * 8 + jj] = e1w[f];
                e1bc[kc * 8 + jj] = e1b[f];
            }
        short8v E2A[2];   // A[m=d(col<8)][k=h feature, permuted]
        #pragma unroll
        for (int kc = 0; kc < 2; ++kc)
            #pragma unroll
            for (int jj = 0; jj < 8; ++jj)
                E2A[kc][jj] = (short)(col < 8
                    ? bfr(e2w[(kc * 32 + (jj >> 2) * 16 + quad * 4 + (jj & 3)) * 8 + col]) : 0);
        float e2bc[4];
        #pragma unroll
        for (int r = 0; r < 4; ++r) e2bc[r] = (quad < 2) ? e2b[quad * 4 + r] : 0.f;

        const int tbase = wv * 16;
        #pragma unroll 1
        for (int nn = 0; nn < 16; ++nn) {
            const float xs = x_l[nn * 130 + tbase + col];
            short8v eB[2];
            #pragma unroll
            for (int kc = 0; kc < 2; ++kc)
                #pragma unroll
                for (int jj = 0; jj < 8; ++jj)
                    eB[kc][jj] = bft(fmaxf(fmaf(xs, e1c[kc * 8 + jj], e1bc[kc * 8 + jj]), 0.f));
            f32x4 d = MFMA32(E2A[0], eB[0], z4);
            d = MFMA32(E2A[1], eB[1], d);
            if (quad < 2) {
                #pragma unroll
                for (int r = 0; r < 4; ++r)
                    enc_l[(tbase + col) * 128 + nn * 8 + quad * 4 + r] = bfr(ftanh(d[r] + e2bc[r]));
            }
        }
    }
    __syncthreads();   // enc_l ready

    if (wv == 0) {
        // =========================== SCANNER ===========================
        short8v A2f[16];   // out m=mt*16+col -> d=mt>>1, j-half=mt&1; k=i (permuted)
        #pragma unroll
        for (int mt = 0; mt < 16; ++mt)
            #pragma unroll
            for (int jj = 0; jj < 8; ++jj)
                A2f[mt][jj] = (short)bfr(
                    A[((jj >> 2) * 16 + quad * 4 + (jj & 3)) * 256 + (mt >> 1) * 32 + (mt & 1) * 16 + col]);

        short8v tmpB;
        #pragma unroll
        for (int jj = 0; jj < 8; ++jj)
            tmpB[jj] = (short)bfr(initw[(jj >> 2) * 16 + quad * 4 + (jj & 3)]);

        asm volatile("s_setprio 2");

        float evc[8];   // ev(enc[0]) for advance t=1, converted off-chain
        {
            const short8v e80 = *(const short8v*)&enc_l[0 * 128 + col * 8];
            #pragma unroll
            for (int d = 0; d < 8; ++d) evc[d] = bf2f((unsigned short)e80[d]);
        }

        #pragma unroll 1
        for (int b = 0; b <= NB; ++b) {
            if (b < NB) {
                #pragma unroll 1
                for (int i = 0; i < BATCH; ++i) {
                    const int t = b * BATCH + i;
                    if (t > 0) {
                        const short8v e8n = *(const short8v*)&enc_l[t * 128 + col * 8]; // for t+1
                        f32x4 D[16];
                        #pragma unroll
                        for (int mt = 0; mt < 16; ++mt) D[mt] = MFMA32(A2f[mt], tmpB, z4);
                        short8v nt;
                        #pragma unroll
                        for (int h = 0; h < 2; ++h)
                            #pragma unroll
                            for (int r = 0; r < 4; ++r) {   // tree combine, D tile mt=2d+h
                                const float p0 = fmaf(evc[1], D[2 + h][r], evc[0] * D[h][r]);
                                const float p1 = fmaf(evc[3], D[6 + h][r], evc[2] * D[4 + h][r]);
                                const float p2 = fmaf(evc[5], D[10 + h][r], evc[4] * D[8 + h][r]);
                                const float p3 = fmaf(evc[7], D[14 + h][r], evc[6] * D[12 + h][r]);
                                nt[h * 4 + r] = bft((p0 + p1) + (p2 + p3));
                            }
                        tmpB = nt;
                        #pragma unroll
                        for (int d = 0; d < 8; ++d) evc[d] = bf2f((unsigned short)e8n[d]);
                    }
                    ring_l[b & 1][i][lane] = tmpB;
                }
            }
            __syncthreads();
        }
        if (lane < 16) part_l[0][lane] = 0.f;
    } else if (wv == 4) {
        // ===== IDLE SIMD0-MATE: frees issue bandwidth for the scanner =====
        asm volatile("s_setprio 0");
        #pragma unroll 1
        for (int b = 0; b <= NB; ++b) __syncthreads();
        if (lane < 16) part_l[4][lane] = 0.f;
    } else {
        // ====== CONSUMERS: waves {1,2,3,5,6,7}; steps cw, cw+6, cw+12 ======
        const int cw = wv - 1 - (wv > 4 ? 1 : 0);   // 0..5
        short8v W1f[4];    // h1 out = mt*16+col, k = th feature (permuted)
        #pragma unroll
        for (int mt = 0; mt < 4; ++mt)
            #pragma unroll
            for (int jj = 0; jj < 8; ++jj)
                W1f[mt][jj] = (short)bfr(n1w[((jj >> 2) * 16 + quad * 4 + (jj & 3)) * 64 + mt * 16 + col]);
        short8v W2f[4][2];
        #pragma unroll
        for (int mt = 0; mt < 4; ++mt)
            #pragma unroll
            for (int kb = 0; kb < 2; ++kb)
                #pragma unroll
                for (int jj = 0; jj < 8; ++jj)
                    W2f[mt][kb][jj] = (short)bfr(
                        n2w[(kb * 32 + (jj >> 2) * 16 + quad * 4 + (jj & 3)) * 64 + mt * 16 + col]);
        short8v Whf[3][2]; // 0=mu,1=sig,2=alpha; out m = head idx (col<10)
        #pragma unroll
        for (int mt = 0; mt < 3; ++mt) {
            const float* Wh = (mt == 0) ? muw : (mt == 1) ? sgw : alw;
            #pragma unroll
            for (int kb = 0; kb < 2; ++kb)
                #pragma unroll
                for (int jj = 0; jj < 8; ++jj)
                    Whf[mt][kb][jj] = (short)(col < 10
                        ? bfr(Wh[(kb * 32 + (jj >> 2) * 16 + quad * 4 + (jj & 3)) * 10 + col]) : 0);
        }
        // epilogue selection matrix (verified R10): D row m%4==0 sums e1 slots
        // (jj<4) of valid heads -> s1; m%4==1 sums e2 slots (jj>=4) -> s2.
        short8v AselF;
        #pragma unroll
        for (int jj = 0; jj < 8; ++jj) {
            const int h = quad * 4 + (jj & 3), half = jj >> 2;
            const int want = (col & 3);
            AselF[jj] = (short)((h < 10 && ((want == 0 && half == 0) || (want == 1 && half == 1)))
                                ? 0x3F80 : 0);
        }

        float res2 = 0.f;
        const float CST = 0.91893853320467274f;

        #pragma unroll 1
        for (int b = 0; b <= NB; ++b) {
            if (b >= 1) {
                #pragma unroll 1
                for (int i = cw; i < BATCH; i += 6) {   // cw<4: 3 steps; else 2
                    const int t = (b - 1) * BATCH + i;
                    const short8v tf = ring_l[(b - 1) & 1][i][lane];
                    short8v thB;
                    #pragma unroll
                    for (int jj = 0; jj < 8; ++jj)
                        thB[jj] = bft(ftanh(bf2f((unsigned short)tf[jj])));

                    // h1 = relu(W1^T @ th + b1)   (bias as C operand)
                    short8v h1B[2];
                    #pragma unroll
                    for (int mt = 0; mt < 4; ++mt) {
                        const f32x4 c = *(const f32x4*)&n1b_l[mt * 16 + quad * 4];
                        const f32x4 d = MFMA32(W1f[mt], thB, c);
                        #pragma unroll
                        for (int r = 0; r < 4; ++r)
                            h1B[mt >> 1][(mt & 1) * 4 + r] = bft(fmaxf(d[r], 0.f));
                    }
                    // h2 = relu(W2^T @ h1 + b2)
                    short8v h2B[2];
                    #pragma unroll
                    for (int mt = 0; mt < 4; ++mt) {
                        const f32x4 c = *(const f32x4*)&n2b_l[mt * 16 + quad * 4];
                        f32x4 d = MFMA32(W2f[mt][0], h1B[0], c);
                        d = MFMA32(W2f[mt][1], h1B[1], d);
                        #pragma unroll
                        for (int r = 0; r < 4; ++r)
                            h2B[mt >> 1][(mt & 1) * 4 + r] = bft(fmaxf(d[r], 0.f));
                    }
                    // heads; lane holds heads quad*4+r for sample col
                    f32x4 hd[3];
                    #pragma unroll
                    for (int mt = 0; mt < 3; ++mt) {
                        const f32x4 c = *(const f32x4*)&hb_l[mt * 16 + quad * 4];
                        f32x4 d = MFMA32(Whf[mt][0], h2B[0], c);
                        hd[mt] = MFMA32(Whf[mt][1], h2B[1], d);
                    }
                    // epilogue: exp terms packed bf16; ONE MFMA does both sums.
                    // (no-max logsumexp: terms O(1); underflow->0 == reference's 0)
                    const float xt = x_l[col * 130 + t];
                    short8v eBv;
                    #pragma unroll
                    for (int r = 0; r < 4; ++r) {
                        const float mu = hd[0][r], sg = hd[1][r], la = hd[2][r];
                        const float z = (xt - mu) * __expf(-sg);
                        eBv[r]     = bft(__expf(la));
                        eBv[4 + r] = bft(__expf(la - sg - fmaf(0.5f * z, z, CST)));
                    }
                    const f32x4 dsum = MFMA32(AselF, eBv, z4);   // [0]=s1, [1]=s2
                    res2 += __log2f(dsum[1]) - __log2f(dsum[0]);
                }
            }
            __syncthreads();
        }
        if (lane < 16) part_l[wv][lane] = res2;   // identical across quads
    }

    __syncthreads();
    if (tid < 16) {
        float s = 0.f;
        #pragma unroll
        for (int w = 0; w < 8; ++w) s += part_l[w][tid];
        out[n0 + tid] = exp2f(s);
    }
}

extern "C" void kernel_launch(void* const* d_in, const int* in_sizes, int n_in,
                              void* d_out, int out_size, void* d_ws, size_t ws_size,
                              hipStream_t stream) {
    wfa_kernel<<<dim3(NN / 16), dim3(512), 0, stream>>>(
        (const float*)d_in[0],  (const float*)d_in[1],  (const float*)d_in[2],
        (const float*)d_in[3],  (const float*)d_in[4],  (const float*)d_in[5],
        (const float*)d_in[6],  (const float*)d_in[7],  (const float*)d_in[8],
        (const float*)d_in[9],  (const float*)d_in[10], (const float*)d_in[11],
        (const float*)d_in[12], (const float*)d_in[13], (const float*)d_in[14],
        (const float*)d_in[15], (const float*)d_in[16], (float*)d_out);
}